// Round 6
// baseline (112.352 us; speedup 1.0000x reference)
//
#include <hip/hip_runtime.h>
#include <hip/hip_bf16.h>
#include <math.h>

#define NV 12
#define BATCH 4096
#define DIM 128
#define ALPHA_C 0.4f
#define BETA_C 2.0f
#define LAMDA_C 2.0f
#define BPB 4          // batch elements per block, one wave each
#define NB (BATCH / BPB)
#define HPAD 136       // hi/lo row pad (shorts): 272B rows, 16B-aligned for b128
#define GPAD 26        // Gram row stride (floats): <=2-way bank alias

typedef short short8 __attribute__((ext_vector_type(8)));
typedef float f32x16 __attribute__((ext_vector_type(16)));

// 256 threads = 4 waves; each wave owns one batch element. LDS use is
// wave-local through the argmin (no barrier needed; lgkmcnt covers RAW).
// Per b: G = X.X^T via 32x32x16 bf16 MFMA with hi/lo split precision,
// X = [12 A-rows; 12 N-rows]. Final reduction fused via last-block-done:
// agent-scope atomics so partials cross the non-coherent per-XCD L2s.
__global__ __launch_bounds__(256) void perb_kernel(
    const float* __restrict__ SV_A, const float* __restrict__ SV_N,
    const float* __restrict__ MV_A, const float* __restrict__ MV_N,
    float* __restrict__ partials, unsigned int* __restrict__ counter,
    float* __restrict__ out)
{
    const int wave = threadIdx.x >> 6;
    const int lane = threadIdx.x & 63;
    const int b    = blockIdx.x * BPB + wave;

    __shared__ __align__(16) unsigned short Hi[BPB][24][HPAD];
    __shared__ __align__(16) unsigned short Lo[BPB][24][HPAD];
    __shared__ __align__(16) float G[BPB][24][GPAD];
    __shared__ float comm[BPB][5];
    __shared__ int   lastf;

    // ---- prefetch MV rows ----
    const size_t mvoff = (size_t)b * DIM + lane;
    const float ma0 = MV_A[mvoff];
    const float ma1 = MV_A[mvoff + 64];
    const float mn0 = MV_N[mvoff];
    const float mn1 = MV_N[mvoff + 64];

    // ---- stage: global float4 -> bf16 hi/lo planes via v_cvt_pk_bf16_f32 ----
    {
        const int half = lane >> 5;
        const int c4   = (lane & 31) * 4;
        #pragma unroll
        for (int rr = 0; rr < NV / 2; ++rr) {
            const int i = 2 * rr + half;
            const size_t off = ((size_t)(i * BATCH + b)) * DIM + c4;
            #pragma unroll
            for (int arr = 0; arr < 2; ++arr) {
                const float4 v = *(const float4*)((arr ? SV_N : SV_A) + off);
                const __hip_bfloat162 h01 = __float22bfloat162_rn({v.x, v.y});
                const __hip_bfloat162 h23 = __float22bfloat162_rn({v.z, v.w});
                const float lx = v.x - __bfloat162float(h01.x);
                const float ly = v.y - __bfloat162float(h01.y);
                const float lz = v.z - __bfloat162float(h23.x);
                const float lw_ = v.w - __bfloat162float(h23.y);
                const __hip_bfloat162 l01 = __float22bfloat162_rn({lx, ly});
                const __hip_bfloat162 l23 = __float22bfloat162_rn({lz, lw_});
                const int row = arr * NV + i;
                uint2 hw, lw;
                hw.x = *(const unsigned int*)&h01;
                hw.y = *(const unsigned int*)&h23;
                lw.x = *(const unsigned int*)&l01;
                lw.y = *(const unsigned int*)&l23;
                *(uint2*)&Hi[wave][row][c4] = hw;
                *(uint2*)&Lo[wave][row][c4] = lw;
            }
        }
    }

    // ---- Gram via MFMA: A-frag == B-frag for X.X^T ----
    // frag layout 32x32x16: elem j of lane = X[lane&31][(lane>>5)*8 + j + 16*kb]
    {
        int r = lane & 31;
        if (r >= 24) r = 0;                    // pad rows: duplicate row 0, ignored
        const int h = lane >> 5;
        const unsigned short* hbase = &Hi[wave][r][h * 8];
        const unsigned short* lbase = &Lo[wave][r][h * 8];
        f32x16 acc = {0.f, 0.f, 0.f, 0.f, 0.f, 0.f, 0.f, 0.f,
                      0.f, 0.f, 0.f, 0.f, 0.f, 0.f, 0.f, 0.f};
        #pragma unroll
        for (int kb = 0; kb < 8; ++kb) {
            const short8 hv = *(const short8*)(hbase + kb * 16);
            const short8 lv = *(const short8*)(lbase + kb * 16);
            acc = __builtin_amdgcn_mfma_f32_32x32x16_bf16(hv, hv, acc, 0, 0, 0);
            acc = __builtin_amdgcn_mfma_f32_32x32x16_bf16(hv, lv, acc, 0, 0, 0);
            acc = __builtin_amdgcn_mfma_f32_32x32x16_bf16(lv, hv, acc, 0, 0, 0);
        }
        // C/D: col = lane&31, row = (reg&3) + 8*(reg>>2) + 4*(lane>>5)
        const int col = lane & 31;
        if (col < 24) {
            #pragma unroll
            for (int rg = 0; rg < 12; ++rg) {   // rg>=12 -> rows>=24, skip
                const int row = (rg & 3) + 8 * (rg >> 2) + 4 * h;
                G[wave][row][col] = acc[rg];
            }
        }
    }

    // ---- distances from G: 2x2 pair tile, lanes 0..35 ----
    float best_d = 3.4e38f;
    int   best_p = 1 << 20;
    if (lane < 36) {
        const int i2 = lane / 6;
        const int j2 = lane % 6;
        const int ia0 = 2 * i2, ia1 = 2 * i2 + 1;
        const int jn0 = 12 + 2 * j2, jn1 = jn0 + 1;
        const float2 g0 = *(const float2*)&G[wave][ia0][jn0];
        const float2 g1 = *(const float2*)&G[wave][ia1][jn0];
        const float na0 = G[wave][ia0][ia0];
        const float na1 = G[wave][ia1][ia1];
        const float nn0 = G[wave][jn0][jn0];
        const float nn1 = G[wave][jn1][jn1];
        const float d00 = na0 + nn0 - 2.f * g0.x;
        const float d01 = na0 + nn1 - 2.f * g0.y;
        const float d10 = na1 + nn0 - 2.f * g1.x;
        const float d11 = na1 + nn1 - 2.f * g1.y;
        const int p00 = ia0 * NV + 2 * j2;     // ascending flat-p: strict <
        best_d = d00; best_p = p00;
        if (d01 < best_d) { best_d = d01; best_p = p00 + 1; }
        if (d10 < best_d) { best_d = d10; best_p = p00 + NV; }
        if (d11 < best_d) { best_d = d11; best_p = p00 + NV + 1; }
    }
    #pragma unroll
    for (int off = 32; off > 0; off >>= 1) {
        const float od = __shfl_down(best_d, off, 64);
        const int   op = __shfl_down(best_p, off, 64);
        if (od < best_d || (od == best_d && op < best_p)) { best_d = od; best_p = op; }
    }
    best_d = __shfl(best_d, 0, 64);
    best_p = __shfl(best_p, 0, 64);

    const int istar = best_p / NV;
    const int jstar = best_p % NV;

    // ---- exact fp32 cluster norms: winning rows re-read from global ----
    float sa, sc, sm;
    {
        const size_t offA = ((size_t)(istar * BATCH + b)) * DIM + lane;
        const size_t offN = ((size_t)(jstar * BATCH + b)) * DIM + lane;
        const float fa0 = SV_A[offA];
        const float fa1 = SV_A[offA + 64];
        const float fn0 = SV_N[offN];
        const float fn1 = SV_N[offN + 64];
        float d1;
        d1 = ma0 - fa0; sa  = d1 * d1;
        d1 = ma1 - fa1; sa += d1 * d1;
        d1 = mn0 - fn0; sc  = d1 * d1;
        d1 = mn1 - fn1; sc += d1 * d1;
        d1 = ma0 - mn0; sm  = d1 * d1;
        d1 = ma1 - mn1; sm += d1 * d1;
    }
    #pragma unroll
    for (int off = 32; off > 0; off >>= 1) {
        sa += __shfl_down(sa, off, 64);
        sc += __shfl_down(sc, off, 64);
        sm += __shfl_down(sm, off, 64);
    }

    if (lane == 0) {
        const float mc    = fmaxf(best_d, 0.f);
        const float a_cl  = sqrtf(sa);
        const float c_in  = sqrtf(sc);
        const float mv_in = sqrtf(sm);
        const float loss  = LAMDA_C * (fmaxf(BETA_C - mc, 0.f) + fmaxf(BETA_C - mv_in, 0.f))
                          + fmaxf(a_cl - ALPHA_C, 0.f) + fmaxf(c_in - ALPHA_C, 0.f);
        const float z = sqrtf(mc);
        comm[wave][0] = loss;
        comm[wave][1] = (loss != 0.f) ? 1.f : 0.f;
        comm[wave][2] = z;
        comm[wave][3] = 0.5f * (sqrtf(a_cl) + sqrtf(c_in));
        comm[wave][4] = z;
    }
    __syncthreads();

    // ---- per-block partial -> agent-scope stores; last block finalizes ----
    if (threadIdx.x == 0) {
        float sl = 0.f, sn = 0.f, ss = 0.f, sh = 0.f, mn = 3.4e38f;
        #pragma unroll
        for (int w = 0; w < BPB; ++w) {
            sl += comm[w][0]; sn += comm[w][1]; ss += comm[w][2]; sh += comm[w][3];
            mn = fminf(mn, comm[w][4]);
        }
        float* rec = partials + (size_t)blockIdx.x * 8;
        __hip_atomic_store(&rec[0], sl, __ATOMIC_RELAXED, __HIP_MEMORY_SCOPE_AGENT);
        __hip_atomic_store(&rec[1], sn, __ATOMIC_RELAXED, __HIP_MEMORY_SCOPE_AGENT);
        __hip_atomic_store(&rec[2], ss, __ATOMIC_RELAXED, __HIP_MEMORY_SCOPE_AGENT);
        __hip_atomic_store(&rec[3], sh, __ATOMIC_RELAXED, __HIP_MEMORY_SCOPE_AGENT);
        __hip_atomic_store(&rec[4], mn, __ATOMIC_RELAXED, __HIP_MEMORY_SCOPE_AGENT);
        const unsigned int old =
            __hip_atomic_fetch_add(counter, 1u, __ATOMIC_ACQ_REL, __HIP_MEMORY_SCOPE_AGENT);
        lastf = (old == NB - 1) ? 1 : 0;
    }
    __syncthreads();

    if (lastf) {
        const int t = threadIdx.x;
        float sl = 0.f, sn = 0.f, ss = 0.f, sh = 0.f, mn = 3.4e38f;
        #pragma unroll
        for (int u = 0; u < NB / 256; ++u) {
            const float* rec = partials + (size_t)(t + u * 256) * 8;
            sl += __hip_atomic_load(&rec[0], __ATOMIC_RELAXED, __HIP_MEMORY_SCOPE_AGENT);
            sn += __hip_atomic_load(&rec[1], __ATOMIC_RELAXED, __HIP_MEMORY_SCOPE_AGENT);
            ss += __hip_atomic_load(&rec[2], __ATOMIC_RELAXED, __HIP_MEMORY_SCOPE_AGENT);
            sh += __hip_atomic_load(&rec[3], __ATOMIC_RELAXED, __HIP_MEMORY_SCOPE_AGENT);
            mn = fminf(mn,
                 __hip_atomic_load(&rec[4], __ATOMIC_RELAXED, __HIP_MEMORY_SCOPE_AGENT));
        }
        #pragma unroll
        for (int off = 32; off > 0; off >>= 1) {
            sl += __shfl_down(sl, off, 64);
            sn += __shfl_down(sn, off, 64);
            ss += __shfl_down(ss, off, 64);
            sh += __shfl_down(sh, off, 64);
            mn = fminf(mn, __shfl_down(mn, off, 64));
        }
        if ((t & 63) == 0) {
            comm[t >> 6][0] = sl; comm[t >> 6][1] = sn; comm[t >> 6][2] = ss;
            comm[t >> 6][3] = sh; comm[t >> 6][4] = mn;
        }
        __syncthreads();
        if (t == 0) {
            #pragma unroll
            for (int w = 1; w < BPB; ++w) {
                sl += comm[w][0]; sn += comm[w][1]; ss += comm[w][2]; sh += comm[w][3];
                mn = fminf(mn, comm[w][4]);
            }
            const float inv = 1.0f / (float)BATCH;
            out[0] = sl * inv;   // avg_loss
            out[1] = sn;         // count_nonzero
            out[2] = ss * inv;   // mean(sqrt(mc_inter))
            out[3] = sh * inv;   // 0.5*(mean sqrt(a_clstr) + mean sqrt(c_intra))
            out[4] = mn;         // min(sqrt(mc_inter))
        }
    }
}

extern "C" void kernel_launch(void* const* d_in, const int* in_sizes, int n_in,
                              void* d_out, int out_size, void* d_ws, size_t ws_size,
                              hipStream_t stream) {
    const float* SV_A = (const float*)d_in[0];
    const float* SV_N = (const float*)d_in[1];
    const float* MV_A = (const float*)d_in[2];
    const float* MV_N = (const float*)d_in[3];
    float* out = (float*)d_out;

    float* partials = (float*)d_ws;                         // NB*8 floats = 32 KiB
    unsigned int* counter = (unsigned int*)((char*)d_ws + NB * 8 * sizeof(float));

    hipMemsetAsync(counter, 0, sizeof(unsigned int), stream);
    perb_kernel<<<NB, 256, 0, stream>>>(SV_A, SV_N, MV_A, MV_N, partials, counter, out);
}

// Round 7
// 95.543 us; speedup vs baseline: 1.1759x; 1.1759x over previous
//
#include <hip/hip_runtime.h>
#include <hip/hip_bf16.h>
#include <math.h>

#define NV 12
#define BATCH 4096
#define DIM 128
#define ALPHA_C 0.4f
#define BETA_C 2.0f
#define LAMDA_C 2.0f
#define BPB 4          // batch elements per block, one wave each
#define NB (BATCH / BPB)
#define HPAD 136       // hi/lo row pad (shorts): 272B rows, 16B-aligned for b128
#define GPAD 26        // Gram row stride (floats): <=2-way bank alias

typedef short short8 __attribute__((ext_vector_type(8)));
typedef float f32x16 __attribute__((ext_vector_type(16)));

// 256 threads = 4 waves; each wave owns one batch element. LDS use is
// wave-local through the argmin (no barrier; lgkmcnt covers same-wave RAW).
// Per b: G = X.X^T via 32x32x16 bf16 MFMA with hi/lo split precision,
// X = [12 A-rows; 12 N-rows]. Block writes ONE 8-float partial record
// (plain stores; kernel boundary provides cross-XCD visibility — R6 showed
// per-block agent-scope atomics cost ~15 us in wb/inv traffic).
__global__ __launch_bounds__(256) void perb_kernel(
    const float* __restrict__ SV_A, const float* __restrict__ SV_N,
    const float* __restrict__ MV_A, const float* __restrict__ MV_N,
    float4* __restrict__ partials)
{
    const int wave = threadIdx.x >> 6;
    const int lane = threadIdx.x & 63;
    const int b    = blockIdx.x * BPB + wave;

    __shared__ __align__(16) unsigned short Hi[BPB][24][HPAD];
    __shared__ __align__(16) unsigned short Lo[BPB][24][HPAD];
    __shared__ __align__(16) float G[BPB][24][GPAD];
    __shared__ float comm[BPB][5];

    // ---- prefetch MV rows ----
    const size_t mvoff = (size_t)b * DIM + lane;
    const float ma0 = MV_A[mvoff];
    const float ma1 = MV_A[mvoff + 64];
    const float mn0 = MV_N[mvoff];
    const float mn1 = MV_N[mvoff + 64];

    // ---- stage: global float4 -> bf16 hi/lo planes (packed cvt) ----
    {
        const int half = lane >> 5;
        const int c4   = (lane & 31) * 4;
        #pragma unroll
        for (int rr = 0; rr < NV / 2; ++rr) {
            const int i = 2 * rr + half;
            const size_t off = ((size_t)(i * BATCH + b)) * DIM + c4;
            #pragma unroll
            for (int arr = 0; arr < 2; ++arr) {
                const float4 v = *(const float4*)((arr ? SV_N : SV_A) + off);
                const __hip_bfloat162 h01 = __float22bfloat162_rn({v.x, v.y});
                const __hip_bfloat162 h23 = __float22bfloat162_rn({v.z, v.w});
                const float lx = v.x - __bfloat162float(h01.x);
                const float ly = v.y - __bfloat162float(h01.y);
                const float lz = v.z - __bfloat162float(h23.x);
                const float lw_ = v.w - __bfloat162float(h23.y);
                const __hip_bfloat162 l01 = __float22bfloat162_rn({lx, ly});
                const __hip_bfloat162 l23 = __float22bfloat162_rn({lz, lw_});
                const int row = arr * NV + i;
                uint2 hw, lw;
                hw.x = *(const unsigned int*)&h01;
                hw.y = *(const unsigned int*)&h23;
                lw.x = *(const unsigned int*)&l01;
                lw.y = *(const unsigned int*)&l23;
                *(uint2*)&Hi[wave][row][c4] = hw;
                *(uint2*)&Lo[wave][row][c4] = lw;
            }
        }
    }

    // ---- Gram via MFMA: A-frag == B-frag for X.X^T ----
    // frag layout 32x32x16: elem j of lane = X[lane&31][(lane>>5)*8 + j + 16*kb]
    {
        int r = lane & 31;
        if (r >= 24) r = 0;                    // pad rows: duplicate row 0, ignored
        const int h = lane >> 5;
        const unsigned short* hbase = &Hi[wave][r][h * 8];
        const unsigned short* lbase = &Lo[wave][r][h * 8];
        f32x16 acc = {0.f, 0.f, 0.f, 0.f, 0.f, 0.f, 0.f, 0.f,
                      0.f, 0.f, 0.f, 0.f, 0.f, 0.f, 0.f, 0.f};
        #pragma unroll
        for (int kb = 0; kb < 8; ++kb) {
            const short8 hv = *(const short8*)(hbase + kb * 16);
            const short8 lv = *(const short8*)(lbase + kb * 16);
            acc = __builtin_amdgcn_mfma_f32_32x32x16_bf16(hv, hv, acc, 0, 0, 0);
            acc = __builtin_amdgcn_mfma_f32_32x32x16_bf16(hv, lv, acc, 0, 0, 0);
            acc = __builtin_amdgcn_mfma_f32_32x32x16_bf16(lv, hv, acc, 0, 0, 0);
        }
        // C/D: col = lane&31, row = (reg&3) + 8*(reg>>2) + 4*(lane>>5)
        const int col = lane & 31;
        if (col < 24) {
            #pragma unroll
            for (int rg = 0; rg < 12; ++rg) {   // rg>=12 -> rows>=24, skip
                const int row = (rg & 3) + 8 * (rg >> 2) + 4 * h;
                G[wave][row][col] = acc[rg];
            }
        }
    }

    // ---- distances from G: 2x2 pair tile, lanes 0..35 ----
    float best_d = 3.4e38f;
    int   best_p = 1 << 20;
    if (lane < 36) {
        const int i2 = lane / 6;
        const int j2 = lane % 6;
        const int ia0 = 2 * i2, ia1 = 2 * i2 + 1;
        const int jn0 = 12 + 2 * j2, jn1 = jn0 + 1;
        const float2 g0 = *(const float2*)&G[wave][ia0][jn0];
        const float2 g1 = *(const float2*)&G[wave][ia1][jn0];
        const float na0 = G[wave][ia0][ia0];
        const float na1 = G[wave][ia1][ia1];
        const float nn0 = G[wave][jn0][jn0];
        const float nn1 = G[wave][jn1][jn1];
        const float d00 = na0 + nn0 - 2.f * g0.x;
        const float d01 = na0 + nn1 - 2.f * g0.y;
        const float d10 = na1 + nn0 - 2.f * g1.x;
        const float d11 = na1 + nn1 - 2.f * g1.y;
        const int p00 = ia0 * NV + 2 * j2;     // ascending flat-p: strict <
        best_d = d00; best_p = p00;
        if (d01 < best_d) { best_d = d01; best_p = p00 + 1; }
        if (d10 < best_d) { best_d = d10; best_p = p00 + NV; }
        if (d11 < best_d) { best_d = d11; best_p = p00 + NV + 1; }
    }
    #pragma unroll
    for (int off = 32; off > 0; off >>= 1) {
        const float od = __shfl_down(best_d, off, 64);
        const int   op = __shfl_down(best_p, off, 64);
        if (od < best_d || (od == best_d && op < best_p)) { best_d = od; best_p = op; }
    }
    best_d = __shfl(best_d, 0, 64);
    best_p = __shfl(best_p, 0, 64);

    const int istar = best_p / NV;
    const int jstar = best_p % NV;

    // ---- exact fp32 cluster norms: winning rows re-read from global ----
    float sa, sc, sm;
    {
        const size_t offA = ((size_t)(istar * BATCH + b)) * DIM + lane;
        const size_t offN = ((size_t)(jstar * BATCH + b)) * DIM + lane;
        const float fa0 = SV_A[offA];
        const float fa1 = SV_A[offA + 64];
        const float fn0 = SV_N[offN];
        const float fn1 = SV_N[offN + 64];
        float d1;
        d1 = ma0 - fa0; sa  = d1 * d1;
        d1 = ma1 - fa1; sa += d1 * d1;
        d1 = mn0 - fn0; sc  = d1 * d1;
        d1 = mn1 - fn1; sc += d1 * d1;
        d1 = ma0 - mn0; sm  = d1 * d1;
        d1 = ma1 - mn1; sm += d1 * d1;
    }
    #pragma unroll
    for (int off = 32; off > 0; off >>= 1) {
        sa += __shfl_down(sa, off, 64);
        sc += __shfl_down(sc, off, 64);
        sm += __shfl_down(sm, off, 64);
    }

    if (lane == 0) {
        const float mc    = fmaxf(best_d, 0.f);
        const float a_cl  = sqrtf(sa);
        const float c_in  = sqrtf(sc);
        const float mv_in = sqrtf(sm);
        const float loss  = LAMDA_C * (fmaxf(BETA_C - mc, 0.f) + fmaxf(BETA_C - mv_in, 0.f))
                          + fmaxf(a_cl - ALPHA_C, 0.f) + fmaxf(c_in - ALPHA_C, 0.f);
        const float z = sqrtf(mc);
        comm[wave][0] = loss;
        comm[wave][1] = (loss != 0.f) ? 1.f : 0.f;
        comm[wave][2] = z;
        comm[wave][3] = 0.5f * (sqrtf(a_cl) + sqrtf(c_in));
        comm[wave][4] = z;
    }
    __syncthreads();

    // ---- per-block combine -> one 32B record (plain stores) ----
    if (threadIdx.x == 0) {
        float sl = 0.f, sn = 0.f, ss = 0.f, sh = 0.f, mn = 3.4e38f;
        #pragma unroll
        for (int w = 0; w < BPB; ++w) {
            sl += comm[w][0]; sn += comm[w][1]; ss += comm[w][2]; sh += comm[w][3];
            mn = fminf(mn, comm[w][4]);
        }
        partials[2 * blockIdx.x]     = make_float4(sl, sn, ss, sh);
        partials[2 * blockIdx.x + 1] = make_float4(mn, 0.f, 0.f, 0.f);
    }
}

// Single-block deterministic final reduction: 256 threads x 4 records.
__global__ __launch_bounds__(256) void final_kernel(
    const float4* __restrict__ partials, float* __restrict__ out)
{
    const int t = threadIdx.x;
    float sl = 0.f, sn = 0.f, ss = 0.f, sh = 0.f, mnv = 3.4e38f;
    #pragma unroll
    for (int u = 0; u < NB / 256; ++u) {
        const int idx = t + u * 256;
        const float4 v = partials[2 * idx];
        const float4 m = partials[2 * idx + 1];
        sl += v.x; sn += v.y; ss += v.z; sh += v.w;
        mnv = fminf(mnv, m.x);
    }
    #pragma unroll
    for (int off = 32; off > 0; off >>= 1) {
        sl += __shfl_down(sl, off, 64);
        sn += __shfl_down(sn, off, 64);
        ss += __shfl_down(ss, off, 64);
        sh += __shfl_down(sh, off, 64);
        mnv = fminf(mnv, __shfl_down(mnv, off, 64));
    }
    __shared__ float r[4][5];
    const int w = t >> 6;
    if ((t & 63) == 0) {
        r[w][0] = sl; r[w][1] = sn; r[w][2] = ss; r[w][3] = sh; r[w][4] = mnv;
    }
    __syncthreads();
    if (t == 0) {
        #pragma unroll
        for (int i = 1; i < 4; ++i) {
            sl += r[i][0]; sn += r[i][1]; ss += r[i][2]; sh += r[i][3];
            mnv = fminf(mnv, r[i][4]);
        }
        const float inv = 1.0f / (float)BATCH;
        out[0] = sl * inv;   // avg_loss
        out[1] = sn;         // count_nonzero
        out[2] = ss * inv;   // mean(sqrt(mc_inter))
        out[3] = sh * inv;   // 0.5*(mean sqrt(a_clstr) + mean sqrt(c_intra))
        out[4] = mnv;        // min(sqrt(mc_inter))
    }
}

extern "C" void kernel_launch(void* const* d_in, const int* in_sizes, int n_in,
                              void* d_out, int out_size, void* d_ws, size_t ws_size,
                              hipStream_t stream) {
    const float* SV_A = (const float*)d_in[0];
    const float* SV_N = (const float*)d_in[1];
    const float* MV_A = (const float*)d_in[2];
    const float* MV_N = (const float*)d_in[3];
    float* out = (float*)d_out;
    float4* partials = (float4*)d_ws;   // NB * 32B = 32 KiB

    perb_kernel<<<NB, 256, 0, stream>>>(SV_A, SV_N, MV_A, MV_N, partials);
    final_kernel<<<1, 256, 0, stream>>>(partials, out);
}